// Round 1
// baseline (21195.068 us; speedup 1.0000x reference)
//
#include <hip/hip_runtime.h>

// CfC actor-critic forward: B=256, T=1024, OBS=32, H=128, A=8.
// One batch row per workgroup (256 WGs, persistent over all T steps).
// Weights live in registers (f32). Wta+Wtb merged (ts=1.0).
// Heads (mean/value) computed inline, one step behind, during combine phase.

#define T_STEPS 1024
#define OBS 32
#define H 128
#define A_DIM 8
#define NT 512  // threads per block (8 waves)

__device__ __forceinline__ float fast_rcp(float x) { return __builtin_amdgcn_rcpf(x); }

__device__ __forceinline__ float fast_tanh(float x) {
    // tanh(x) = 1 - 2/(exp(2x)+1); exp overflow->inf handled (rcp(inf)=0)
    float e = __expf(2.0f * x);
    return 1.0f - 2.0f * fast_rcp(e + 1.0f);
}

__device__ __forceinline__ float fast_sigmoid(float x) {
    return fast_rcp(1.0f + __expf(-x));
}

template<int NV>
__device__ __forceinline__ float dotp(const float* zb, const float* w) {
    const float4* z4 = (const float4*)zb;
    float ax = 0.f, ay = 0.f, az = 0.f, aw = 0.f;
#pragma unroll
    for (int v = 0; v < NV; ++v) {
        float4 zz = z4[v];
        ax = fmaf(zz.x, w[4 * v + 0], ax);
        ay = fmaf(zz.y, w[4 * v + 1], ay);
        az = fmaf(zz.z, w[4 * v + 2], az);
        aw = fmaf(zz.w, w[4 * v + 3], aw);
    }
    return (ax + ay) + (az + aw);
}

__device__ __forceinline__ float fetchW(const float* Wff1, const float* Wff2,
                                        const float* Wta, const float* Wtb,
                                        int o, int k) {
    int m = o >> 7, j = o & 127;
    if (m == 0) return Wff1[k * H + j];
    if (m == 1) return Wff2[k * H + j];
    return Wta[k * H + j] + Wtb[k * H + j];  // merged time matrix
}

__global__ __launch_bounds__(NT, 2) void cfc_kernel(
    const float* __restrict__ obs,
    const float* __restrict__ Wb,  const float* __restrict__ bb,
    const float* __restrict__ Wff1, const float* __restrict__ bff1,
    const float* __restrict__ Wff2, const float* __restrict__ bff2,
    const float* __restrict__ Wta, const float* __restrict__ bta,
    const float* __restrict__ Wtb, const float* __restrict__ btb,
    const float* __restrict__ Wa,  const float* __restrict__ ba,
    const float* __restrict__ Wc,  const float* __restrict__ bc,
    float* __restrict__ out_mean, float* __restrict__ out_value)
{
    const int b = blockIdx.x;
    const int t = threadIdx.x;
    const float* obsb = obs + (size_t)b * T_STEPS * OBS;

    __shared__ __align__(16) float hbuf[2][136];  // h double-buffer, padded (pads zeroed)
    __shared__ __align__(16) float zbuf[H];       // backbone output
    __shared__ __align__(16) float xbuf[4][48];   // obs ring (pads zeroed)
    __shared__ __align__(16) float part[384][2];  // phase-B partials per output

    // ---------------- init LDS ----------------
    if (t < 136) hbuf[1][t] = 0.0f;
    if (t >= 192 && t < 200) hbuf[0][128 + (t - 192)] = 0.0f;
    if (t >= 256 && t < 320) { int r = (t - 256) >> 4, c = 32 + ((t - 256) & 15); xbuf[r][c] = 0.0f; }
    if (t >= 320 && t < 352) xbuf[0][t - 320] = obsb[t - 320];
    if (t >= 384 && t < 416) xbuf[1][t - 384] = obsb[OBS + (t - 384)];

    // ---------------- phase A weights (backbone 160x128), t = 4*j + p ----------------
    const int jA = t >> 2, pA = t & 3;
    // concat-k split: p0: x[0:32]; p1: h[0:44]; p2: h[44:88]; p3: h[88:128]
    const int k0A  = (pA == 0) ? 0 : (pA == 1 ? 32 : (pA == 2 ? 76 : 120));
    const int lenA = (pA == 0) ? 32 : (pA == 3 ? 40 : 44);
    const int hoffA = (pA == 1) ? 0 : (pA == 2 ? 44 : 88);
    float wAr[44];
#pragma unroll
    for (int i = 0; i < 44; ++i) {
        int kk = k0A + i; if (kk > 159) kk = 159;
        wAr[i] = (i < lenA) ? Wb[kk * H + jA] : 0.0f;
    }
    const float bbj = bb[jA];

    // ---------------- phase B weights, t = p*128 + g (p wave-uniform) ----------------
    const int pB = t >> 7, g = t & 127;
    float wBr[96];
    if (pB == 0) {
#pragma unroll
        for (int i = 0; i < 96; ++i) wBr[i] = fetchW(Wff1, Wff2, Wta, Wtb, 3 * g, i);
    } else if (pB == 1) {
#pragma unroll
        for (int i = 0; i < 32; ++i) wBr[i] = fetchW(Wff1, Wff2, Wta, Wtb, 3 * g, 96 + i);
#pragma unroll
        for (int i = 0; i < 64; ++i) wBr[32 + i] = fetchW(Wff1, Wff2, Wta, Wtb, 3 * g + 1, i);
    } else if (pB == 2) {
#pragma unroll
        for (int i = 0; i < 64; ++i) wBr[i] = fetchW(Wff1, Wff2, Wta, Wtb, 3 * g + 1, 64 + i);
#pragma unroll
        for (int i = 0; i < 32; ++i) wBr[64 + i] = fetchW(Wff1, Wff2, Wta, Wtb, 3 * g + 2, i);
    } else {
#pragma unroll
        for (int i = 0; i < 96; ++i) wBr[i] = fetchW(Wff1, Wff2, Wta, Wtb, 3 * g + 2, 32 + i);
    }

    // ---------------- combine-phase biases (threads < 128) ----------------
    float bff1j = 0.f, bff2j = 0.f, btj = 0.f;
    if (t < 128) { bff1j = bff1[t]; bff2j = bff2[t]; btj = bta[t] + btb[t]; }

    // ---------------- head weights (threads 128..415): a = group, q = lane-in-32 ----------------
    float wH0 = 0.f, wH1 = 0.f, wH2 = 0.f, wH3 = 0.f, bH = 0.f;
    int aH = 0, qH = 0;
    if (t >= 128 && t < 416) {
        int hi = t - 128;
        aH = hi >> 5; qH = hi & 31;
        if (aH < 8) {
            wH0 = Wa[(qH * 4 + 0) * A_DIM + aH];
            wH1 = Wa[(qH * 4 + 1) * A_DIM + aH];
            wH2 = Wa[(qH * 4 + 2) * A_DIM + aH];
            wH3 = Wa[(qH * 4 + 3) * A_DIM + aH];
            bH = ba[aH];
        } else {
            wH0 = Wc[qH * 4 + 0]; wH1 = Wc[qH * 4 + 1];
            wH2 = Wc[qH * 4 + 2]; wH3 = Wc[qH * 4 + 3];
            bH = bc[0];
        }
    }

    __syncthreads();

    // ================= main sequential loop =================
    for (int st = 0; st < T_STEPS; ++st) {
        // ---- phase A: z = lecun_tanh([x,h] @ Wb + bb) ----
        {
            const float* zinA = (pA == 0) ? &xbuf[st & 3][0] : &hbuf[(st + 1) & 1][hoffA];
            float s = dotp<11>(zinA, wAr);
            s += __shfl_xor(s, 1);
            s += __shfl_xor(s, 2);
            if (pA == 0) zbuf[jA] = 1.7159f * fast_tanh(0.666f * (s + bbj));
        }
        __syncthreads();

        // ---- phase B: 384 dots of length 128 (3 outputs per 4-thread column) ----
        {
            if (pB == 0) {
                part[3 * g][0] = dotp<24>(zbuf, wBr);
            } else if (pB == 1) {
                part[3 * g][1]     = dotp<8>(zbuf + 96, wBr);
                part[3 * g + 1][0] = dotp<16>(zbuf, wBr + 32);
            } else if (pB == 2) {
                part[3 * g + 1][1] = dotp<16>(zbuf + 64, wBr);
                part[3 * g + 2][0] = dotp<8>(zbuf, wBr + 64);
            } else {
                part[3 * g + 2][1] = dotp<24>(zbuf + 32, wBr);
            }
        }
        __syncthreads();

        // ---- combine (t<128) | heads for st-1 (128..415) | obs prefetch st+2 (416..447) ----
        if (t < 128) {
            float a0 = part[t][0] + part[t][1] + bff1j;
            float a1 = part[128 + t][0] + part[128 + t][1] + bff2j;
            float a2 = part[256 + t][0] + part[256 + t][1] + btj;
            float ff1 = fast_tanh(a0);
            float ff2 = fast_tanh(a1);
            float ti  = fast_sigmoid(a2);
            hbuf[st & 1][t] = ff1 + ti * (ff2 - ff1);
        } else if (t < 416) {
            if (st > 0) {
                const float* hp = &hbuf[(st + 1) & 1][qH * 4];
                float4 hv = *(const float4*)hp;
                float d = fmaf(hv.x, wH0, fmaf(hv.y, wH1, fmaf(hv.z, wH2, hv.w * wH3)));
                d += __shfl_xor(d, 1);
                d += __shfl_xor(d, 2);
                d += __shfl_xor(d, 4);
                d += __shfl_xor(d, 8);
                d += __shfl_xor(d, 16);
                if (qH == 0) {
                    int s = st - 1;
                    if (aH < 8) out_mean[((size_t)b * T_STEPS + s) * A_DIM + aH] = d + bH;
                    else        out_value[(size_t)b * T_STEPS + s] = d + bH;
                }
            }
        } else if (t < 448) {
            int lane = t - 416;
            int tf = st + 2;
            if (tf < T_STEPS) xbuf[tf & 3][lane] = obsb[(size_t)tf * OBS + lane];
        }
        __syncthreads();
    }

    // ---- final heads for s = T-1 (h in hbuf[(T-1)&1]) ----
    if (t >= 128 && t < 416) {
        const float* hp = &hbuf[(T_STEPS - 1) & 1][qH * 4];
        float4 hv = *(const float4*)hp;
        float d = fmaf(hv.x, wH0, fmaf(hv.y, wH1, fmaf(hv.z, wH2, hv.w * wH3)));
        d += __shfl_xor(d, 1);
        d += __shfl_xor(d, 2);
        d += __shfl_xor(d, 4);
        d += __shfl_xor(d, 8);
        d += __shfl_xor(d, 16);
        if (qH == 0) {
            int s = T_STEPS - 1;
            if (aH < 8) out_mean[((size_t)b * T_STEPS + s) * A_DIM + aH] = d + bH;
            else        out_value[(size_t)b * T_STEPS + s] = d + bH;
        }
    }
}

extern "C" void kernel_launch(void* const* d_in, const int* in_sizes, int n_in,
                              void* d_out, int out_size, void* d_ws, size_t ws_size,
                              hipStream_t stream) {
    (void)in_sizes; (void)n_in; (void)d_ws; (void)ws_size; (void)out_size;
    const float* obs  = (const float*)d_in[0];
    const float* Wb   = (const float*)d_in[1];
    const float* bb   = (const float*)d_in[2];
    const float* Wff1 = (const float*)d_in[3];
    const float* bff1 = (const float*)d_in[4];
    const float* Wff2 = (const float*)d_in[5];
    const float* bff2 = (const float*)d_in[6];
    const float* Wta  = (const float*)d_in[7];
    const float* bta  = (const float*)d_in[8];
    const float* Wtb  = (const float*)d_in[9];
    const float* btb  = (const float*)d_in[10];
    const float* Wa   = (const float*)d_in[11];
    const float* ba   = (const float*)d_in[12];
    const float* Wc   = (const float*)d_in[13];
    const float* bc   = (const float*)d_in[14];
    float* out = (float*)d_out;
    float* out_mean  = out;
    float* out_value = out + (size_t)256 * 1024 * 8;

    cfc_kernel<<<dim3(256), dim3(512), 0, stream>>>(
        obs, Wb, bb, Wff1, bff1, Wff2, bff2, Wta, bta, Wtb, btb,
        Wa, ba, Wc, bc, out_mean, out_value);
}

// Round 2
// 21164.105 us; speedup vs baseline: 1.0015x; 1.0015x over previous
//
#include <hip/hip_runtime.h>

// CfC actor-critic forward: B=256, T=1024, OBS=32, H=128, A=8.
// One batch row per workgroup (256 WGs, persistent over all T steps).
// Weights live in registers (f32). Wta+Wtb merged (ts=1.0).
// Heads (mean/value) computed inline, one step behind, during combine phase.
//
// R1 lesson: __launch_bounds__(512,2) gave a 128-VGPR budget -> 140 weight
// floats/thread spilled to scratch -> 21.4 GB HBM fetch, 21 ms. Fix: pin
// 2 waves/EU (256-VGPR budget) via amdgpu_waves_per_eu(2,2).

#define T_STEPS 1024
#define OBS 32
#define H 128
#define A_DIM 8
#define NT 512  // threads per block (8 waves)

__device__ __forceinline__ float fast_rcp(float x) { return __builtin_amdgcn_rcpf(x); }

__device__ __forceinline__ float fast_tanh(float x) {
    // tanh(x) = 1 - 2/(exp(2x)+1); exp overflow->inf handled (rcp(inf)=0)
    float e = __expf(2.0f * x);
    return 1.0f - 2.0f * fast_rcp(e + 1.0f);
}

__device__ __forceinline__ float fast_sigmoid(float x) {
    return fast_rcp(1.0f + __expf(-x));
}

template<int NV>
__device__ __forceinline__ float dotp(const float* zb, const float* w) {
    const float4* z4 = (const float4*)zb;
    float ax = 0.f, ay = 0.f, az = 0.f, aw = 0.f;
#pragma unroll
    for (int v = 0; v < NV; ++v) {
        float4 zz = z4[v];
        ax = fmaf(zz.x, w[4 * v + 0], ax);
        ay = fmaf(zz.y, w[4 * v + 1], ay);
        az = fmaf(zz.z, w[4 * v + 2], az);
        aw = fmaf(zz.w, w[4 * v + 3], aw);
    }
    return (ax + ay) + (az + aw);
}

__device__ __forceinline__ float fetchW(const float* Wff1, const float* Wff2,
                                        const float* Wta, const float* Wtb,
                                        int o, int k) {
    int m = o >> 7, j = o & 127;
    if (m == 0) return Wff1[k * H + j];
    if (m == 1) return Wff2[k * H + j];
    return Wta[k * H + j] + Wtb[k * H + j];  // merged time matrix
}

__attribute__((amdgpu_waves_per_eu(2, 2)))
__global__ void __launch_bounds__(NT) cfc_kernel(
    const float* __restrict__ obs,
    const float* __restrict__ Wb,  const float* __restrict__ bb,
    const float* __restrict__ Wff1, const float* __restrict__ bff1,
    const float* __restrict__ Wff2, const float* __restrict__ bff2,
    const float* __restrict__ Wta, const float* __restrict__ bta,
    const float* __restrict__ Wtb, const float* __restrict__ btb,
    const float* __restrict__ Wa,  const float* __restrict__ ba,
    const float* __restrict__ Wc,  const float* __restrict__ bc,
    float* __restrict__ out_mean, float* __restrict__ out_value)
{
    const int b = blockIdx.x;
    const int t = threadIdx.x;
    const float* obsb = obs + (size_t)b * T_STEPS * OBS;

    __shared__ __align__(16) float hbuf[2][136];  // h double-buffer, padded (pads zeroed)
    __shared__ __align__(16) float zbuf[H];       // backbone output
    __shared__ __align__(16) float xbuf[4][48];   // obs ring (pads zeroed)
    __shared__ __align__(16) float part[384][2];  // phase-B partials per output

    // ---------------- init LDS ----------------
    if (t < 136) hbuf[1][t] = 0.0f;
    if (t >= 192 && t < 200) hbuf[0][128 + (t - 192)] = 0.0f;
    if (t >= 256 && t < 320) { int r = (t - 256) >> 4, c = 32 + ((t - 256) & 15); xbuf[r][c] = 0.0f; }
    if (t >= 320 && t < 352) xbuf[0][t - 320] = obsb[t - 320];
    if (t >= 384 && t < 416) xbuf[1][t - 384] = obsb[OBS + (t - 384)];

    // ---------------- phase A weights (backbone 160x128), t = 4*j + p ----------------
    const int jA = t >> 2, pA = t & 3;
    // concat-k split: p0: x[0:32]; p1: h[0:44]; p2: h[44:88]; p3: h[88:128]
    const int k0A  = (pA == 0) ? 0 : (pA == 1 ? 32 : (pA == 2 ? 76 : 120));
    const int lenA = (pA == 0) ? 32 : (pA == 3 ? 40 : 44);
    const int hoffA = (pA == 1) ? 0 : (pA == 2 ? 44 : 88);
    float wAr[44];
#pragma unroll
    for (int i = 0; i < 44; ++i) {
        int kk = k0A + i; if (kk > 159) kk = 159;
        wAr[i] = (i < lenA) ? Wb[kk * H + jA] : 0.0f;
    }
    const float bbj = bb[jA];

    // ---------------- phase B weights, t = p*128 + g (p wave-uniform) ----------------
    const int pB = t >> 7, g = t & 127;
    float wBr[96];
    if (pB == 0) {
#pragma unroll
        for (int i = 0; i < 96; ++i) wBr[i] = fetchW(Wff1, Wff2, Wta, Wtb, 3 * g, i);
    } else if (pB == 1) {
#pragma unroll
        for (int i = 0; i < 32; ++i) wBr[i] = fetchW(Wff1, Wff2, Wta, Wtb, 3 * g, 96 + i);
#pragma unroll
        for (int i = 0; i < 64; ++i) wBr[32 + i] = fetchW(Wff1, Wff2, Wta, Wtb, 3 * g + 1, i);
    } else if (pB == 2) {
#pragma unroll
        for (int i = 0; i < 64; ++i) wBr[i] = fetchW(Wff1, Wff2, Wta, Wtb, 3 * g + 1, 64 + i);
#pragma unroll
        for (int i = 0; i < 32; ++i) wBr[64 + i] = fetchW(Wff1, Wff2, Wta, Wtb, 3 * g + 2, i);
    } else {
#pragma unroll
        for (int i = 0; i < 96; ++i) wBr[i] = fetchW(Wff1, Wff2, Wta, Wtb, 3 * g + 2, 32 + i);
    }

    // ---------------- combine-phase biases (threads < 128) ----------------
    float bff1j = 0.f, bff2j = 0.f, btj = 0.f;
    if (t < 128) { bff1j = bff1[t]; bff2j = bff2[t]; btj = bta[t] + btb[t]; }

    // ---------------- head weights (threads 128..415): a = group, q = lane-in-32 ----------------
    float wH0 = 0.f, wH1 = 0.f, wH2 = 0.f, wH3 = 0.f, bH = 0.f;
    int aH = 0, qH = 0;
    if (t >= 128 && t < 416) {
        int hi = t - 128;
        aH = hi >> 5; qH = hi & 31;
        if (aH < 8) {
            wH0 = Wa[(qH * 4 + 0) * A_DIM + aH];
            wH1 = Wa[(qH * 4 + 1) * A_DIM + aH];
            wH2 = Wa[(qH * 4 + 2) * A_DIM + aH];
            wH3 = Wa[(qH * 4 + 3) * A_DIM + aH];
            bH = ba[aH];
        } else {
            wH0 = Wc[qH * 4 + 0]; wH1 = Wc[qH * 4 + 1];
            wH2 = Wc[qH * 4 + 2]; wH3 = Wc[qH * 4 + 3];
            bH = bc[0];
        }
    }

    __syncthreads();

    // ================= main sequential loop =================
    for (int st = 0; st < T_STEPS; ++st) {
        // ---- phase A: z = lecun_tanh([x,h] @ Wb + bb) ----
        {
            const float* zinA = (pA == 0) ? &xbuf[st & 3][0] : &hbuf[(st + 1) & 1][hoffA];
            float s = dotp<11>(zinA, wAr);
            s += __shfl_xor(s, 1);
            s += __shfl_xor(s, 2);
            if (pA == 0) zbuf[jA] = 1.7159f * fast_tanh(0.666f * (s + bbj));
        }
        __syncthreads();

        // ---- phase B: 384 dots of length 128 (3 outputs per 4-thread column) ----
        {
            if (pB == 0) {
                part[3 * g][0] = dotp<24>(zbuf, wBr);
            } else if (pB == 1) {
                part[3 * g][1]     = dotp<8>(zbuf + 96, wBr);
                part[3 * g + 1][0] = dotp<16>(zbuf, wBr + 32);
            } else if (pB == 2) {
                part[3 * g + 1][1] = dotp<16>(zbuf + 64, wBr);
                part[3 * g + 2][0] = dotp<8>(zbuf, wBr + 64);
            } else {
                part[3 * g + 2][1] = dotp<24>(zbuf + 32, wBr);
            }
        }
        __syncthreads();

        // ---- combine (t<128) | heads for st-1 (128..415) | obs prefetch st+2 (416..447) ----
        if (t < 128) {
            float a0 = part[t][0] + part[t][1] + bff1j;
            float a1 = part[128 + t][0] + part[128 + t][1] + bff2j;
            float a2 = part[256 + t][0] + part[256 + t][1] + btj;
            float ff1 = fast_tanh(a0);
            float ff2 = fast_tanh(a1);
            float ti  = fast_sigmoid(a2);
            hbuf[st & 1][t] = ff1 + ti * (ff2 - ff1);
        } else if (t < 416) {
            if (st > 0) {
                const float* hp = &hbuf[(st + 1) & 1][qH * 4];
                float4 hv = *(const float4*)hp;
                float d = fmaf(hv.x, wH0, fmaf(hv.y, wH1, fmaf(hv.z, wH2, hv.w * wH3)));
                d += __shfl_xor(d, 1);
                d += __shfl_xor(d, 2);
                d += __shfl_xor(d, 4);
                d += __shfl_xor(d, 8);
                d += __shfl_xor(d, 16);
                if (qH == 0) {
                    int s = st - 1;
                    if (aH < 8) out_mean[((size_t)b * T_STEPS + s) * A_DIM + aH] = d + bH;
                    else        out_value[(size_t)b * T_STEPS + s] = d + bH;
                }
            }
        } else if (t < 448) {
            int lane = t - 416;
            int tf = st + 2;
            if (tf < T_STEPS) xbuf[tf & 3][lane] = obsb[(size_t)tf * OBS + lane];
        }
        __syncthreads();
    }

    // ---- final heads for s = T-1 (h in hbuf[(T-1)&1]) ----
    if (t >= 128 && t < 416) {
        const float* hp = &hbuf[(T_STEPS - 1) & 1][qH * 4];
        float4 hv = *(const float4*)hp;
        float d = fmaf(hv.x, wH0, fmaf(hv.y, wH1, fmaf(hv.z, wH2, hv.w * wH3)));
        d += __shfl_xor(d, 1);
        d += __shfl_xor(d, 2);
        d += __shfl_xor(d, 4);
        d += __shfl_xor(d, 8);
        d += __shfl_xor(d, 16);
        if (qH == 0) {
            int s = T_STEPS - 1;
            if (aH < 8) out_mean[((size_t)b * T_STEPS + s) * A_DIM + aH] = d + bH;
            else        out_value[(size_t)b * T_STEPS + s] = d + bH;
        }
    }
}

extern "C" void kernel_launch(void* const* d_in, const int* in_sizes, int n_in,
                              void* d_out, int out_size, void* d_ws, size_t ws_size,
                              hipStream_t stream) {
    (void)in_sizes; (void)n_in; (void)d_ws; (void)ws_size; (void)out_size;
    const float* obs  = (const float*)d_in[0];
    const float* Wb   = (const float*)d_in[1];
    const float* bb   = (const float*)d_in[2];
    const float* Wff1 = (const float*)d_in[3];
    const float* bff1 = (const float*)d_in[4];
    const float* Wff2 = (const float*)d_in[5];
    const float* bff2 = (const float*)d_in[6];
    const float* Wta  = (const float*)d_in[7];
    const float* bta  = (const float*)d_in[8];
    const float* Wtb  = (const float*)d_in[9];
    const float* btb  = (const float*)d_in[10];
    const float* Wa   = (const float*)d_in[11];
    const float* ba   = (const float*)d_in[12];
    const float* Wc   = (const float*)d_in[13];
    const float* bc   = (const float*)d_in[14];
    float* out = (float*)d_out;
    float* out_mean  = out;
    float* out_value = out + (size_t)256 * 1024 * 8;

    cfc_kernel<<<dim3(256), dim3(512), 0, stream>>>(
        obs, Wb, bb, Wff1, bff1, Wff2, bff2, Wta, bta, Wtb, btb,
        Wa, ba, Wc, bc, out_mean, out_value);
}

// Round 3
// 1680.978 us; speedup vs baseline: 12.6088x; 12.5904x over previous
//
#include <hip/hip_runtime.h>

// CfC actor-critic forward: B=256, T=1024, OBS=32, H=128, A=8.
// One batch row per workgroup (256 WGs, persistent over all T steps).
// R2 lesson: 512-thread design needed ~140 weights/thread -> needs 256 VGPRs,
// but compiler pinned 128 VGPRs regardless of waves_per_eu/launch_bounds ->
// wholesale spill -> 21 GB scratch fetch. Redesign for the 128-VGPR budget:
// 1024 threads/block, <=85 weight floats per thread, head weights aliased
// into the same wB array so divergent roles share register live ranges.

#define T_STEPS 1024
#define OBS 32
#define H 128
#define A_DIM 8
#define NT 1024  // 16 waves, 1 block/CU -> 4 waves/EU -> 128-VGPR budget

__device__ __forceinline__ float fast_rcp(float x) { return __builtin_amdgcn_rcpf(x); }

__device__ __forceinline__ float fast_tanh(float x) {
    float e = __expf(2.0f * x);
    return 1.0f - 2.0f * fast_rcp(e + 1.0f);
}

__device__ __forceinline__ float fast_sigmoid(float x) {
    return fast_rcp(1.0f + __expf(-x));
}

template<int NV>
__device__ __forceinline__ float dotp(const float* zb, const float* w) {
    const float4* z4 = (const float4*)zb;
    float ax = 0.f, ay = 0.f, az = 0.f, aw = 0.f;
#pragma unroll
    for (int v = 0; v < NV; ++v) {
        float4 zz = z4[v];
        ax = fmaf(zz.x, w[4 * v + 0], ax);
        ay = fmaf(zz.y, w[4 * v + 1], ay);
        az = fmaf(zz.z, w[4 * v + 2], az);
        aw = fmaf(zz.w, w[4 * v + 3], aw);
    }
    return (ax + ay) + (az + aw);
}

__global__ void __launch_bounds__(NT) cfc_kernel(
    const float* __restrict__ obs,
    const float* __restrict__ Wb,  const float* __restrict__ bb,
    const float* __restrict__ Wff1, const float* __restrict__ bff1,
    const float* __restrict__ Wff2, const float* __restrict__ bff2,
    const float* __restrict__ Wta, const float* __restrict__ bta,
    const float* __restrict__ Wtb, const float* __restrict__ btb,
    const float* __restrict__ Wa,  const float* __restrict__ ba,
    const float* __restrict__ Wc,  const float* __restrict__ bc,
    float* __restrict__ out_mean, float* __restrict__ out_value)
{
    const int b = blockIdx.x;
    const int t = threadIdx.x;
    const float* obsb = obs + (size_t)b * T_STEPS * OBS;

    // zin[cur] = [ x(st) (32) | h(st-1) (128) ]  -- contiguous 160-vec
    __shared__ __align__(16) float zin[2][160];
    __shared__ __align__(16) float zbuf[H];    // backbone output z(st)
    __shared__ __align__(16) float part[384];  // fully-reduced gate pre-activations

    // ---------------- roles ----------------
    const int jA = t >> 3, sA = t & 7;            // phase A: 8 threads per output j
    const bool isB = (t < 768);
    const int oB = t >> 1, sB = t & 1;            // phase B: 2 threads per output o
    const bool isH = (t >= 768 && t < 912);       // heads: 9 outs x 16 threads
    const int oH = (t - 768) >> 4, sH = (t - 768) & 15;
    const bool isX = (t >= 912 && t < 944);       // obs prefetch
    const int lx = t - 912;

    // ---------------- phase A weights: Wb chunk [sA*20 .. sA*20+20) x col jA ----
    float wA[20];
#pragma unroll
    for (int i = 0; i < 20; ++i) wA[i] = Wb[(sA * 20 + i) * H + jA];
    const float bbj = (sA == 0) ? bb[jA] : 0.0f;

    // ---------------- wB: gate weights (t<768) OR head weights (768..911) ----
    float wB[64];
    if (isB) {
        const int m = oB >> 7, j = oB & 127;
        if (m == 0) {
#pragma unroll
            for (int i = 0; i < 64; ++i) wB[i] = Wff1[(sB * 64 + i) * H + j];
        } else if (m == 1) {
#pragma unroll
            for (int i = 0; i < 64; ++i) wB[i] = Wff2[(sB * 64 + i) * H + j];
        } else {
#pragma unroll
            for (int i = 0; i < 64; ++i) wB[i] = Wta[(sB * 64 + i) * H + j] + Wtb[(sB * 64 + i) * H + j];
        }
    } else if (isH) {
        if (oH < 8) {
#pragma unroll
            for (int i = 0; i < 8; ++i) wB[i] = Wa[(sH * 8 + i) * A_DIM + oH];
            wB[8] = ba[oH];
        } else {
#pragma unroll
            for (int i = 0; i < 8; ++i) wB[i] = Wc[sH * 8 + i];
            wB[8] = bc[0];
        }
    }

    // ---------------- combine biases (t<128) ----------------
    float b1 = 0.f, b2 = 0.f, b3 = 0.f;
    if (t < 128) { b1 = bff1[t]; b2 = bff2[t]; b3 = bta[t] + btb[t]; }

    // ---------------- obs prefetch regs ----------------
    float xW = 0.f, xP = 0.f;
    if (isX) { xW = obsb[OBS + lx]; xP = obsb[2 * OBS + lx]; }

    // ---------------- init LDS: zin[0] = [obs[0] | 0] ----------------
    if (t < 32) zin[0][t] = obsb[t];
    else if (t < 160) zin[0][t] = 0.0f;

    __syncthreads();

    // ================= main sequential loop =================
    for (int st = 0; st < T_STEPS; ++st) {
        const int cur = st & 1, nxt = cur ^ 1;

        // ---- phase A: z = lecun_tanh([x,h] @ Wb + bb) ----
        {
            float s = dotp<5>(&zin[cur][sA * 20], wA);
            s += __shfl_xor(s, 1);
            s += __shfl_xor(s, 2);
            s += __shfl_xor(s, 4);
            if (sA == 0) zbuf[jA] = 1.7159f * fast_tanh(0.666f * (s + bbj));
        }
        __syncthreads();

        // ---- phase B: 384 gate dots || heads on h(st-1) ----
        if (isB) {
            float d = dotp<16>(&zbuf[sB * 64], wB);
            d += __shfl_xor(d, 1);
            if (sB == 0) part[oB] = d;
        } else if (isH) {
            if (st > 0) {
                float d = dotp<2>(&zin[cur][32 + sH * 8], wB);
                d += __shfl_xor(d, 1);
                d += __shfl_xor(d, 2);
                d += __shfl_xor(d, 4);
                d += __shfl_xor(d, 8);
                if (sH == 0) {
                    const int s = st - 1;
                    if (oH < 8) out_mean[((size_t)b * T_STEPS + s) * A_DIM + oH] = d + wB[8];
                    else        out_value[(size_t)b * T_STEPS + s] = d + wB[8];
                }
            }
        }
        __syncthreads();

        // ---- combine -> h(st) into zin[nxt] || x(st+1) write + prefetch ----
        if (t < 128) {
            float ff1 = fast_tanh(part[t] + b1);
            float ff2 = fast_tanh(part[128 + t] + b2);
            float ti  = fast_sigmoid(part[256 + t] + b3);
            zin[nxt][32 + t] = ff1 + ti * (ff2 - ff1);
        } else if (isX) {
            zin[nxt][lx] = xW;
            xW = xP;
            const int tf = st + 3;
            xP = (tf < T_STEPS) ? obsb[(size_t)tf * OBS + lx] : 0.0f;
        }
        __syncthreads();
    }

    // ---- final heads for s = T-1: h(T-1) is in zin[T&1] = zin[0] ----
    if (isH) {
        float d = dotp<2>(&zin[0][32 + sH * 8], wB);
        d += __shfl_xor(d, 1);
        d += __shfl_xor(d, 2);
        d += __shfl_xor(d, 4);
        d += __shfl_xor(d, 8);
        if (sH == 0) {
            const int s = T_STEPS - 1;
            if (oH < 8) out_mean[((size_t)b * T_STEPS + s) * A_DIM + oH] = d + wB[8];
            else        out_value[(size_t)b * T_STEPS + s] = d + wB[8];
        }
    }
}

extern "C" void kernel_launch(void* const* d_in, const int* in_sizes, int n_in,
                              void* d_out, int out_size, void* d_ws, size_t ws_size,
                              hipStream_t stream) {
    (void)in_sizes; (void)n_in; (void)d_ws; (void)ws_size; (void)out_size;
    const float* obs  = (const float*)d_in[0];
    const float* Wb   = (const float*)d_in[1];
    const float* bb   = (const float*)d_in[2];
    const float* Wff1 = (const float*)d_in[3];
    const float* bff1 = (const float*)d_in[4];
    const float* Wff2 = (const float*)d_in[5];
    const float* bff2 = (const float*)d_in[6];
    const float* Wta  = (const float*)d_in[7];
    const float* bta  = (const float*)d_in[8];
    const float* Wtb  = (const float*)d_in[9];
    const float* btb  = (const float*)d_in[10];
    const float* Wa   = (const float*)d_in[11];
    const float* ba   = (const float*)d_in[12];
    const float* Wc   = (const float*)d_in[13];
    const float* bc   = (const float*)d_in[14];
    float* out = (float*)d_out;
    float* out_mean  = out;
    float* out_value = out + (size_t)256 * 1024 * 8;

    cfc_kernel<<<dim3(256), dim3(NT), 0, stream>>>(
        obs, Wb, bb, Wff1, bff1, Wff2, bff2, Wta, bta, Wtb, btb,
        Wa, ba, Wc, bc, out_mean, out_value);
}

// Round 5
// 1319.612 us; speedup vs baseline: 16.0616x; 1.2738x over previous
//
#include <hip/hip_runtime.h>

// CfC actor-critic forward: B=256, T=1024, OBS=32, H=128, A=8.
// One batch row per workgroup (256 WGs x 1024 thr, persistent over T steps).
// R4 lesson: row_ror:N rotates data toward HIGHER lanes (dest i reads i-N);
// the "+4" reduce step needs row_ror:12 (dest i reads i+4), not row_ror:4.
// Structure: 2 barriers/step, DPP reductions, zbuf split at 68 floats.

#define T_STEPS 1024
#define OBS 32
#define H 128
#define A_DIM 8
#define NT 1024  // 16 waves, 1 block/CU

// DPP controls
#define QXOR1 0xB1   // quad_perm [1,0,3,2]  == xor 1
#define QXOR2 0x4E   // quad_perm [2,3,0,1]  == xor 2
#define RPLUS4 0x12C // row_ror:12 -> dest lane i reads lane (i+4) & 15

template<int CTRL>
__device__ __forceinline__ float dppmv(float x) {
    int r = __builtin_amdgcn_update_dpp(0, __float_as_int(x), CTRL, 0xF, 0xF, true);
    return __int_as_float(r);
}

__device__ __forceinline__ float fast_rcp(float x) { return __builtin_amdgcn_rcpf(x); }

__device__ __forceinline__ float fast_tanh(float x) {
    float e = __expf(2.0f * x);
    return 1.0f - 2.0f * fast_rcp(e + 1.0f);
}

__device__ __forceinline__ float fast_sigmoid(float x) {
    return fast_rcp(1.0f + __expf(-x));
}

template<int NV>
__device__ __forceinline__ float dotp(const float* zb, const float* w) {
    const float4* z4 = (const float4*)zb;
    float ax = 0.f, ay = 0.f, az = 0.f, aw = 0.f;
#pragma unroll
    for (int v = 0; v < NV; ++v) {
        float4 zz = z4[v];
        ax = fmaf(zz.x, w[4 * v + 0], ax);
        ay = fmaf(zz.y, w[4 * v + 1], ay);
        az = fmaf(zz.z, w[4 * v + 2], az);
        aw = fmaf(zz.w, w[4 * v + 3], aw);
    }
    return (ax + ay) + (az + aw);
}

__global__ void __launch_bounds__(NT) cfc_kernel(
    const float* __restrict__ obs,
    const float* __restrict__ Wb,  const float* __restrict__ bb,
    const float* __restrict__ Wff1, const float* __restrict__ bff1,
    const float* __restrict__ Wff2, const float* __restrict__ bff2,
    const float* __restrict__ Wta, const float* __restrict__ bta,
    const float* __restrict__ Wtb, const float* __restrict__ btb,
    const float* __restrict__ Wa,  const float* __restrict__ ba,
    const float* __restrict__ Wc,  const float* __restrict__ bc,
    float* __restrict__ out_mean, float* __restrict__ out_value)
{
    const int b = blockIdx.x;
    const int t = threadIdx.x;
    const float* obsb = obs + (size_t)b * T_STEPS * OBS;

    // zin[cur] = [ x(st) (32) | h(st-1) (128) ]
    __shared__ __align__(16) float zin[2][160];
    // z(st), split halves at 0 and 68 (bank-decorrelated)
    __shared__ __align__(16) float zbuf[136];

    const int jA = t >> 3, sA = t & 7;   // 8 threads per output j
    const int wv = t >> 6;               // wave id 0..15

    // ---------------- phase-1 weights: Wb[sA*20 .. +20) x col jA ----------------
    float wA[20];
#pragma unroll
    for (int i = 0; i < 20; ++i) wA[i] = Wb[(sA * 20 + i) * H + jA];
    const float bbj = bb[jA];

    // ---------------- phase-2 roles ----------------
    const bool isGate = (sA < 6);
    const int gateG = sA >> 1;           // 0: ff1, 1: ff2, 2: t-interp
    const int gateC = sA & 1;            // k-half
    const int hp = ((jA & 7) << 1) | (sA & 1);  // head lane pos 0..15 (sA>=6)

    float wB[64];
    float b1 = 0.f, b2 = 0.f, b3 = 0.f;
    if (isGate) {
        const int kb = gateC * 64;
        if (gateG == 0) {
#pragma unroll
            for (int i = 0; i < 64; ++i) wB[i] = Wff1[(kb + i) * H + jA];
        } else if (gateG == 1) {
#pragma unroll
            for (int i = 0; i < 64; ++i) wB[i] = Wff2[(kb + i) * H + jA];
        } else {
#pragma unroll
            for (int i = 0; i < 64; ++i) wB[i] = Wta[(kb + i) * H + jA] + Wtb[(kb + i) * H + jA];
        }
        b1 = bff1[jA]; b2 = bff2[jA]; b3 = bta[jA] + btb[jA];
    } else if (wv < 9) {
        // heads: wave wv owns head output wv (0..7 actor, 8 critic); 16 lanes
        if (wv < 8) {
#pragma unroll
            for (int i = 0; i < 8; ++i) wB[i] = Wa[(hp * 8 + i) * A_DIM + wv];
            wB[8] = ba[wv];
        } else {
#pragma unroll
            for (int i = 0; i < 8; ++i) wB[i] = Wc[hp * 8 + i];
            wB[8] = bc[0];
        }
    }

    // obs prefetch lanes: s>=6 lanes of waves 9,10 -> 32 lanes
    const bool isX = (!isGate) && (wv == 9 || wv == 10);
    const int lx = ((wv - 9) << 4) | hp;   // 0..31
    float xW = 0.f, xP = 0.f;
    if (isX) { xW = obsb[OBS + lx]; xP = obsb[2 * OBS + lx]; }

    // ---------------- init zin[0] = [obs[0] | h=0] ----------------
    if (t < 32) zin[0][t] = obsb[t];
    else if (t < 160) zin[0][t] = 0.0f;
    __syncthreads();

    // ================= main sequential loop: 2 barriers/step =================
    for (int st = 0; st < T_STEPS; ++st) {
        const int cur = st & 1, nxt = cur ^ 1;

        // ---- phase 1: z = lecun_tanh([x,h] @ Wb + bb), 8 lanes/output ----
        {
            float s = dotp<5>(&zin[cur][sA * 20], wA);
            s += dppmv<QXOR1>(s);
            s += dppmv<QXOR2>(s);
            s += dppmv<RPLUS4>(s);   // writer lanes (0,8 per row): add +4 quad
            if (sA == 0) {
                float z = 1.7159f * fast_tanh(0.666f * (s + bbj));
                zbuf[(jA < 64) ? jA : (jA + 4)] = z;
            }
        }
        __syncthreads();

        // ---- phase 2: gates + combine -> h(st) | heads(st-1) | obs(st+1) ----
        if (isGate) {
            float d = dotp<16>(&zbuf[gateC * 68], wB);
            d += dppmv<QXOR1>(d);           // pair-reduce: s0=g1, s2=g2, s4=g3
            float g2 = dppmv<QXOR2>(d);     // at s0: value from s2
            float g3 = dppmv<RPLUS4>(d);    // at s0: value from s4
            if (sA == 0) {
                float ff1 = fast_tanh(d + b1);
                float ff2 = fast_tanh(g2 + b2);
                float ti  = fast_sigmoid(g3 + b3);
                zin[nxt][32 + jA] = ff1 + ti * (ff2 - ff1);
            }
        } else if (wv < 9) {
            if (st > 0) {
                float d = dotp<2>(&zin[cur][32 + hp * 8], wB);
                d += __shfl_xor(d, 1);
                d += __shfl_xor(d, 8);
                d += __shfl_xor(d, 16);
                d += __shfl_xor(d, 32);
                if (hp == 0) {
                    const int s_ = st - 1;
                    if (wv < 8) out_mean[((size_t)b * T_STEPS + s_) * A_DIM + wv] = d + wB[8];
                    else        out_value[(size_t)b * T_STEPS + s_] = d + wB[8];
                }
            }
        } else if (isX) {
            zin[nxt][lx] = xW;
            xW = xP;
            const int tf = st + 3;
            xP = (tf < T_STEPS) ? obsb[(size_t)tf * OBS + lx] : 0.0f;
        }
        __syncthreads();
    }

    // ---- final heads for s = T-1: h(T-1) is in zin[0] (T even) ----
    if (!isGate && wv < 9) {
        float d = dotp<2>(&zin[0][32 + hp * 8], wB);
        d += __shfl_xor(d, 1);
        d += __shfl_xor(d, 8);
        d += __shfl_xor(d, 16);
        d += __shfl_xor(d, 32);
        if (hp == 0) {
            const int s_ = T_STEPS - 1;
            if (wv < 8) out_mean[((size_t)b * T_STEPS + s_) * A_DIM + wv] = d + wB[8];
            else        out_value[(size_t)b * T_STEPS + s_] = d + wB[8];
        }
    }
}

extern "C" void kernel_launch(void* const* d_in, const int* in_sizes, int n_in,
                              void* d_out, int out_size, void* d_ws, size_t ws_size,
                              hipStream_t stream) {
    (void)in_sizes; (void)n_in; (void)d_ws; (void)ws_size; (void)out_size;
    const float* obs  = (const float*)d_in[0];
    const float* Wb   = (const float*)d_in[1];
    const float* bb   = (const float*)d_in[2];
    const float* Wff1 = (const float*)d_in[3];
    const float* bff1 = (const float*)d_in[4];
    const float* Wff2 = (const float*)d_in[5];
    const float* bff2 = (const float*)d_in[6];
    const float* Wta  = (const float*)d_in[7];
    const float* bta  = (const float*)d_in[8];
    const float* Wtb  = (const float*)d_in[9];
    const float* btb  = (const float*)d_in[10];
    const float* Wa   = (const float*)d_in[11];
    const float* ba   = (const float*)d_in[12];
    const float* Wc   = (const float*)d_in[13];
    const float* bc   = (const float*)d_in[14];
    float* out = (float*)d_out;
    float* out_mean  = out;
    float* out_value = out + (size_t)256 * 1024 * 8;

    cfc_kernel<<<dim3(256), dim3(NT), 0, stream>>>(
        obs, Wb, bb, Wff1, bff1, Wff2, bff2, Wta, bta, Wtb, btb,
        Wa, ba, Wc, bc, out_mean, out_value);
}

// Round 6
// 1158.692 us; speedup vs baseline: 18.2922x; 1.1389x over previous
//
#include <hip/hip_runtime.h>

// CfC actor-critic forward: B=256, T=1024, OBS=32, H=128, A=8.
// R6: MFMA rewrite. 64 blocks x 4 batch rows (M=16 tile, rows 4-15 padded),
// 8 waves/block. Weights preloaded once as f16 B-fragments in registers.
// Per step: ph1 backbone (5 chained mfma/wave) + heads on wave 7 (shares
// A-frags), z-act -> zf LDS; ph2 gates (3x4 chained mfma/wave), combine ->
// h f16 back into zin. 2 barriers/step. A/B frag k-order is self-consistent
// (sum over k is permutation-invariant); C/D layout is the HW-verified
// col=lane&15, row=(lane>>4)*4+reg.

typedef _Float16 half8 __attribute__((ext_vector_type(8)));
typedef float f32x4 __attribute__((ext_vector_type(4)));

#define T_STEPS 1024
#define OBS 32
#define H 128
#define A_DIM 8
#define NW 8
#define NT (NW * 64)
#define ROWS 4
#define NBLK 64

#define ZIN_P 168   // [16][168] f16: cols 0-31 x, 32-159 h; pitch 336B (16B-aligned)
#define ZF_P 136    // [16][136] f16: z; pitch 272B

__device__ __forceinline__ float fast_rcp(float x) { return __builtin_amdgcn_rcpf(x); }
__device__ __forceinline__ float fast_tanh(float x) {
    float e = __expf(2.0f * x);
    return 1.0f - 2.0f * fast_rcp(e + 1.0f);
}
__device__ __forceinline__ float fast_sigmoid(float x) {
    return fast_rcp(1.0f + __expf(-x));
}

__global__ void __launch_bounds__(NT) cfc_kernel(
    const float* __restrict__ obs,
    const float* __restrict__ Wb,  const float* __restrict__ bb,
    const float* __restrict__ Wff1, const float* __restrict__ bff1,
    const float* __restrict__ Wff2, const float* __restrict__ bff2,
    const float* __restrict__ Wta, const float* __restrict__ bta,
    const float* __restrict__ Wtb, const float* __restrict__ btb,
    const float* __restrict__ Wa,  const float* __restrict__ ba,
    const float* __restrict__ Wc,  const float* __restrict__ bc,
    float* __restrict__ out_mean, float* __restrict__ out_value)
{
    const int b0 = blockIdx.x * ROWS;
    const int tid = threadIdx.x;
    const int w = tid >> 6, l = tid & 63;
    const int lo = l & 15, hi = l >> 4;      // lo: M/N index, hi: k-group

    __shared__ _Float16 zin[16][ZIN_P];      // [x_t | h_{t-1}]
    __shared__ _Float16 zf[16][ZF_P];        // z(t)

    // ---------------- preload B-fragments (f16) ----------------
    // wave w owns output cols [16w, 16w+16) for backbone AND gates.
    const int colB = w * 16 + lo;

    half8 Bb[5];                              // backbone 160xH, 5 k-subtiles
#pragma unroll
    for (int ks = 0; ks < 5; ++ks)
#pragma unroll
        for (int j = 0; j < 8; ++j) {
            int k = ks * 32 + hi * 8 + j;
            Bb[ks][j] = (_Float16)Wb[k * H + colB];
        }
    const float bbv = bb[colB];

    half8 Bg0[4], Bg1[4], Bg2[4];             // gates HxH, 4 k-subtiles
#pragma unroll
    for (int ks = 0; ks < 4; ++ks)
#pragma unroll
        for (int j = 0; j < 8; ++j) {
            int k = ks * 32 + hi * 8 + j;
            Bg0[ks][j] = (_Float16)Wff1[k * H + colB];
            Bg1[ks][j] = (_Float16)Wff2[k * H + colB];
            Bg2[ks][j] = (_Float16)(Wta[k * H + colB] + Wtb[k * H + colB]);
        }
    const float bg1 = bff1[colB], bg2 = bff2[colB], bg3 = bta[colB] + btb[colB];

    half8 Bh[4];                              // heads Hx9 (cols: 0-7 actor, 8 critic)
    float bh = 0.f;
    if (w == 7) {
#pragma unroll
        for (int ks = 0; ks < 4; ++ks)
#pragma unroll
            for (int j = 0; j < 8; ++j) {
                int k = ks * 32 + hi * 8 + j;
                float v = (lo < 8) ? Wa[k * A_DIM + lo] : ((lo == 8) ? Wc[k] : 0.0f);
                Bh[ks][j] = (_Float16)v;
            }
        bh = (lo < 8) ? ba[lo] : ((lo == 8) ? bc[0] : 0.0f);
    }

    // ---------------- init LDS ----------------
    for (int i = tid; i < 16 * ZIN_P; i += NT) (&zin[0][0])[i] = (_Float16)0.0f;
    __syncthreads();
    if (w == 0) {                             // x(0) rows 0-3
        int r = l >> 5, c = l & 31;
        zin[r][c]     = (_Float16)obs[((size_t)(b0 + r) * T_STEPS) * OBS + c];
        zin[r + 2][c] = (_Float16)obs[((size_t)(b0 + r + 2) * T_STEPS) * OBS + c];
    }
    __syncthreads();

    float ox0 = 0.f, ox1 = 0.f;

    // ================= main loop: 2 barriers/step =================
    for (int t = 0; t < T_STEPS; ++t) {
        // obs(t+1) prefetch (wave 0)
        if (w == 0 && t + 1 < T_STEPS) {
            int r = l >> 5, c = l & 31;
            ox0 = obs[((size_t)(b0 + r) * T_STEPS + (t + 1)) * OBS + c];
            ox1 = obs[((size_t)(b0 + r + 2) * T_STEPS + (t + 1)) * OBS + c];
        }

        // ---- phase 1: z = lecun_tanh([x|h] @ Wb + bb) ----
        half8 A0 = *(const half8*)&zin[lo][0 * 32 + hi * 8];
        half8 A1 = *(const half8*)&zin[lo][1 * 32 + hi * 8];
        half8 A2 = *(const half8*)&zin[lo][2 * 32 + hi * 8];
        half8 A3 = *(const half8*)&zin[lo][3 * 32 + hi * 8];
        half8 A4 = *(const half8*)&zin[lo][4 * 32 + hi * 8];
        f32x4 accz = {0.f, 0.f, 0.f, 0.f};
        accz = __builtin_amdgcn_mfma_f32_16x16x32_f16(A0, Bb[0], accz, 0, 0, 0);
        accz = __builtin_amdgcn_mfma_f32_16x16x32_f16(A1, Bb[1], accz, 0, 0, 0);
        accz = __builtin_amdgcn_mfma_f32_16x16x32_f16(A2, Bb[2], accz, 0, 0, 0);
        accz = __builtin_amdgcn_mfma_f32_16x16x32_f16(A3, Bb[3], accz, 0, 0, 0);
        accz = __builtin_amdgcn_mfma_f32_16x16x32_f16(A4, Bb[4], accz, 0, 0, 0);

        // heads on h_{t-1} (wave 7; A1..A4 are exactly the h k-subtiles)
        if (w == 7 && t > 0) {
            f32x4 acch = {0.f, 0.f, 0.f, 0.f};
            acch = __builtin_amdgcn_mfma_f32_16x16x32_f16(A1, Bh[0], acch, 0, 0, 0);
            acch = __builtin_amdgcn_mfma_f32_16x16x32_f16(A2, Bh[1], acch, 0, 0, 0);
            acch = __builtin_amdgcn_mfma_f32_16x16x32_f16(A3, Bh[2], acch, 0, 0, 0);
            acch = __builtin_amdgcn_mfma_f32_16x16x32_f16(A4, Bh[3], acch, 0, 0, 0);
            if (hi == 0 && lo < 9) {
#pragma unroll
                for (int j = 0; j < 4; ++j) {
                    float v = acch[j] + bh;
                    if (lo < 8) out_mean[((size_t)(b0 + j) * T_STEPS + (t - 1)) * A_DIM + lo] = v;
                    else        out_value[(size_t)(b0 + j) * T_STEPS + (t - 1)] = v;
                }
            }
        }

        // z-act -> zf  (C-frag: col=lo -> colB, row=hi*4+j)
#pragma unroll
        for (int j = 0; j < 4; ++j) {
            float zval = 1.7159f * fast_tanh(0.666f * (accz[j] + bbv));
            zf[hi * 4 + j][colB] = (_Float16)zval;
        }
        __syncthreads();

        // ---- phase 2: gates + combine -> h(t) ----
        half8 Z0 = *(const half8*)&zf[lo][0 * 32 + hi * 8];
        half8 Z1 = *(const half8*)&zf[lo][1 * 32 + hi * 8];
        half8 Z2 = *(const half8*)&zf[lo][2 * 32 + hi * 8];
        half8 Z3 = *(const half8*)&zf[lo][3 * 32 + hi * 8];
        f32x4 a1 = {0.f, 0.f, 0.f, 0.f}, a2 = a1, a3 = a1;
        a1 = __builtin_amdgcn_mfma_f32_16x16x32_f16(Z0, Bg0[0], a1, 0, 0, 0);
        a2 = __builtin_amdgcn_mfma_f32_16x16x32_f16(Z0, Bg1[0], a2, 0, 0, 0);
        a3 = __builtin_amdgcn_mfma_f32_16x16x32_f16(Z0, Bg2[0], a3, 0, 0, 0);
        a1 = __builtin_amdgcn_mfma_f32_16x16x32_f16(Z1, Bg0[1], a1, 0, 0, 0);
        a2 = __builtin_amdgcn_mfma_f32_16x16x32_f16(Z1, Bg1[1], a2, 0, 0, 0);
        a3 = __builtin_amdgcn_mfma_f32_16x16x32_f16(Z1, Bg2[1], a3, 0, 0, 0);
        a1 = __builtin_amdgcn_mfma_f32_16x16x32_f16(Z2, Bg0[2], a1, 0, 0, 0);
        a2 = __builtin_amdgcn_mfma_f32_16x16x32_f16(Z2, Bg1[2], a2, 0, 0, 0);
        a3 = __builtin_amdgcn_mfma_f32_16x16x32_f16(Z2, Bg2[2], a3, 0, 0, 0);
        a1 = __builtin_amdgcn_mfma_f32_16x16x32_f16(Z3, Bg0[3], a1, 0, 0, 0);
        a2 = __builtin_amdgcn_mfma_f32_16x16x32_f16(Z3, Bg1[3], a2, 0, 0, 0);
        a3 = __builtin_amdgcn_mfma_f32_16x16x32_f16(Z3, Bg2[3], a3, 0, 0, 0);

#pragma unroll
        for (int j = 0; j < 4; ++j) {
            float ff1 = fast_tanh(a1[j] + bg1);
            float ff2 = fast_tanh(a2[j] + bg2);
            float ti  = fast_sigmoid(a3[j] + bg3);
            float hv  = ff1 + ti * (ff2 - ff1);
            zin[hi * 4 + j][32 + colB] = (_Float16)hv;
        }

        // x(t+1) -> zin (wave 0)
        if (w == 0 && t + 1 < T_STEPS) {
            int r = l >> 5, c = l & 31;
            zin[r][c]     = (_Float16)ox0;
            zin[r + 2][c] = (_Float16)ox1;
        }
        __syncthreads();
    }

    // ---- epilogue: heads for s = T-1 (h_{T-1} now in zin) ----
    if (w == 7) {
        half8 A1 = *(const half8*)&zin[lo][32 + 0 * 32 + hi * 8];
        half8 A2 = *(const half8*)&zin[lo][32 + 1 * 32 + hi * 8];
        half8 A3 = *(const half8*)&zin[lo][32 + 2 * 32 + hi * 8];
        half8 A4 = *(const half8*)&zin[lo][32 + 3 * 32 + hi * 8];
        f32x4 acch = {0.f, 0.f, 0.f, 0.f};
        acch = __builtin_amdgcn_mfma_f32_16x16x32_f16(A1, Bh[0], acch, 0, 0, 0);
        acch = __builtin_amdgcn_mfma_f32_16x16x32_f16(A2, Bh[1], acch, 0, 0, 0);
        acch = __builtin_amdgcn_mfma_f32_16x16x32_f16(A3, Bh[2], acch, 0, 0, 0);
        acch = __builtin_amdgcn_mfma_f32_16x16x32_f16(A4, Bh[3], acch, 0, 0, 0);
        if (hi == 0 && lo < 9) {
#pragma unroll
            for (int j = 0; j < 4; ++j) {
                float v = acch[j] + bh;
                if (lo < 8) out_mean[((size_t)(b0 + j) * T_STEPS + (T_STEPS - 1)) * A_DIM + lo] = v;
                else        out_value[(size_t)(b0 + j) * T_STEPS + (T_STEPS - 1)] = v;
            }
        }
    }
}

extern "C" void kernel_launch(void* const* d_in, const int* in_sizes, int n_in,
                              void* d_out, int out_size, void* d_ws, size_t ws_size,
                              hipStream_t stream) {
    (void)in_sizes; (void)n_in; (void)d_ws; (void)ws_size; (void)out_size;
    const float* obs  = (const float*)d_in[0];
    const float* Wb   = (const float*)d_in[1];
    const float* bb   = (const float*)d_in[2];
    const float* Wff1 = (const float*)d_in[3];
    const float* bff1 = (const float*)d_in[4];
    const float* Wff2 = (const float*)d_in[5];
    const float* bff2 = (const float*)d_in[6];
    const float* Wta  = (const float*)d_in[7];
    const float* bta  = (const float*)d_in[8];
    const float* Wtb  = (const float*)d_in[9];
    const float* btb  = (const float*)d_in[10];
    const float* Wa   = (const float*)d_in[11];
    const float* ba   = (const float*)d_in[12];
    const float* Wc   = (const float*)d_in[13];
    const float* bc   = (const float*)d_in[14];
    float* out = (float*)d_out;
    float* out_mean  = out;
    float* out_value = out + (size_t)256 * 1024 * 8;

    cfc_kernel<<<dim3(NBLK), dim3(NT), 0, stream>>>(
        obs, Wb, bb, Wff1, bff1, Wff2, bff2, Wta, bta, Wtb, btb,
        Wa, ba, Wc, bc, out_mean, out_value);
}